// Round 11
// baseline (313.057 us; speedup 1.0000x reference)
//
#include <hip/hip_runtime.h>
#include <hip/hip_fp16.h>
#include <math.h>

#define N_NODES   80000
#define NU_NODES  40000
#define E_EDGES   1280000
#define B_PAIRS   8192
#define NEG_SLOPE 0.2f
#define NBUCK     313   // ceil(N_NODES / 256)
#define SCHUNK    2048  // edges per bscatter block

typedef _Float16 half8 __attribute__((ext_vector_type(8)));
typedef float    f32x4 __attribute__((ext_vector_type(4)));

// ---------------- CSR row_ptr build: hist + per-bucket scans ----------------

__global__ void hist_kernel(const int* __restrict__ dst, int* __restrict__ counts, int E) {
    int e = blockIdx.x * 256 + threadIdx.x;
    if (e < E) atomicAdd(&counts[dst[e]], 1);
}

__global__ __launch_bounds__(256) void scan256_kernel(const int* __restrict__ counts,
                                                      int* __restrict__ row_ptr,
                                                      int* __restrict__ bsums) {
    __shared__ int tmp[256];
    int t = threadIdx.x;
    int gid = (blockIdx.x << 8) + t;
    int v = (gid < N_NODES) ? counts[gid] : 0;
    tmp[t] = v;
    __syncthreads();
    for (int off = 1; off < 256; off <<= 1) {
        int x = (t >= off) ? tmp[t - off] : 0;
        __syncthreads();
        tmp[t] += x;
        __syncthreads();
    }
    if (gid < N_NODES) row_ptr[gid + 1] = tmp[t];
    if (t == 255) bsums[blockIdx.x] = tmp[255];
}

__global__ __launch_bounds__(512) void topscan_kernel(const int* __restrict__ bsums,
                                                      int* __restrict__ bucket_ptr,
                                                      int* __restrict__ gfill) {
    __shared__ int tmp[512];
    int t = threadIdx.x;
    int v = (t < NBUCK) ? bsums[t] : 0;
    tmp[t] = v;
    __syncthreads();
    for (int off = 1; off < 512; off <<= 1) {
        int x = (t >= off) ? tmp[t - off] : 0;
        __syncthreads();
        tmp[t] += x;
        __syncthreads();
    }
    int excl = tmp[t] - v;
    if (t < NBUCK) {
        bucket_ptr[t] = excl;
        gfill[t]      = excl;
        if (t == NBUCK - 1) bucket_ptr[NBUCK] = excl + v;
    }
}

__global__ void fixup_kernel(int* row_ptr, const int* __restrict__ bucket_ptr) {
    int gid = blockIdx.x * 256 + threadIdx.x;
    if (gid < N_NODES) row_ptr[gid + 1] += bucket_ptr[gid >> 8];
    if (gid == 0) row_ptr[0] = 0;
}

__global__ __launch_bounds__(512) void bscatter_kernel(const int* __restrict__ src,
                                                       const int* __restrict__ dst,
                                                       int* __restrict__ gfill,
                                                       unsigned long long* __restrict__ pk,
                                                       int E) {
    __shared__ int histL[NBUCK];
    __shared__ int baseL[NBUCK];
    __shared__ int rankL[NBUCK];
    for (int i = threadIdx.x; i < NBUCK; i += 512) { histL[i] = 0; rankL[i] = 0; }
    __syncthreads();
    int base = blockIdx.x * SCHUNK;
#pragma unroll
    for (int r = 0; r < SCHUNK / 512; ++r) {
        int e = base + r * 512 + threadIdx.x;
        if (e < E) atomicAdd(&histL[dst[e] >> 8], 1);
    }
    __syncthreads();
    for (int i = threadIdx.x; i < NBUCK; i += 512)
        baseL[i] = histL[i] ? atomicAdd(&gfill[i], histL[i]) : 0;
    __syncthreads();
#pragma unroll
    for (int r = 0; r < SCHUNK / 512; ++r) {
        int e = base + r * 512 + threadIdx.x;
        if (e < E) {
            int d = dst[e];
            int b = d >> 8;
            int rk = atomicAdd(&rankL[b], 1);
            pk[baseL[b] + rk] = ((unsigned long long)(unsigned)d << 32) | (unsigned)src[e];
        }
    }
}

__global__ __launch_bounds__(256) void escatter_kernel(const unsigned long long* __restrict__ pk,
                                                       const int* __restrict__ bucket_ptr,
                                                       const int* __restrict__ row_ptr,
                                                       int* __restrict__ src_sorted) {
    __shared__ int fillL[256];
    __shared__ int rpL[256];
    int b = blockIdx.x;
    int node0 = b << 8;
    int nn = N_NODES - node0; if (nn > 256) nn = 256;
    fillL[threadIdx.x] = 0;
    rpL[threadIdx.x]   = (threadIdx.x < nn) ? row_ptr[node0 + threadIdx.x] : 0;
    __syncthreads();
    int s = bucket_ptr[b], e = bucket_ptr[b + 1];
    for (int k = s + threadIdx.x; k < e; k += 256) {
        unsigned long long p = pk[k];
        int lo = (int)(p >> 32) & 255;
        int pos = atomicAdd(&fillL[lo], 1);
        src_sorted[rpL[lo] + pos] = (int)(unsigned)p;
    }
}

// ---------------- MFMA f16 GEMM + fused attention-dot epilogue ----------------
// h stored as TWO head-major tables h0/h1 [N][64] fp16 (10MB each) so the
// aggregation passes gather from a table half the size (L2 hit-rate lever).

template <int K, bool AF32>
__global__ __launch_bounds__(256) void gemm_mfma(const void* __restrict__ A0v,
                                                 const void* __restrict__ A1v, int split,
                                                 const float* __restrict__ W,
                                                 const float* __restrict__ attS,
                                                 const float* __restrict__ attD,
                                                 __half* __restrict__ h0,
                                                 __half* __restrict__ h1,
                                                 float* __restrict__ a_s,
                                                 float* __restrict__ a_d) {
    constexpr int BSTR   = K + 8;
    constexpr int BSM_SZ = 128 * BSTR * 2;
    constexpr int EPI_SZ = 128 * 136 * 2;
    constexpr int ATT_OFF = (10240 + BSM_SZ > EPI_SZ) ? (10240 + BSM_SZ) : EPI_SZ;
    __shared__ __align__(16) char lds[ATT_OFF + 1024];
    _Float16* Asm  = (_Float16*)lds;
    _Float16* Bsm  = (_Float16*)(lds + 10240);
    _Float16* epi  = (_Float16*)lds;
    float*    attL = (float*)(lds + ATT_OFF);

    const int tid    = threadIdx.x;
    const int w      = tid >> 6;
    const int l      = tid & 63;
    const int l15    = l & 15;
    const int g      = l >> 4;
    const int blkrow = blockIdx.x * 128;

    attL[tid] = (tid < 128) ? attS[tid] : attD[tid - 128];

    for (int idx = tid; idx < K * 32; idx += 256) {
        int k = idx >> 5, c4 = idx & 31;
        float4 wv = *(const float4*)&W[(size_t)k * 128 + c4 * 4];
        Bsm[(c4 * 4 + 0) * BSTR + k] = (_Float16)wv.x;
        Bsm[(c4 * 4 + 1) * BSTR + k] = (_Float16)wv.y;
        Bsm[(c4 * 4 + 2) * BSTR + k] = (_Float16)wv.z;
        Bsm[(c4 * 4 + 3) * BSTR + k] = (_Float16)wv.w;
    }

    const void* rowp[2];
#pragma unroll
    for (int p = 0; p < 2; ++p) {
        int idx = tid + p * 256;
        int row = idx >> 2;
        int grow = blkrow + row;
        if (AF32) {
            const float* A0 = (const float*)A0v;
            const float* A1 = (const float*)A1v;
            rowp[p] = (grow < split) ? (const void*)(A0 + (size_t)grow * K)
                                     : (const void*)(A1 + (size_t)(grow - split) * K);
        } else {
            rowp[p] = (const void*)((const _Float16*)A0v + (size_t)grow * K);
        }
    }

    auto stageA = [&](int c) {
#pragma unroll
        for (int p = 0; p < 2; ++p) {
            int idx = tid + p * 256;
            int row = idx >> 2, kq = idx & 3;
            half8 hv;
            if (AF32) {
                const float* ap = (const float*)rowp[p];
                float4 v0 = *(const float4*)&ap[c * 32 + kq * 8];
                float4 v1 = *(const float4*)&ap[c * 32 + kq * 8 + 4];
                hv[0] = (_Float16)v0.x; hv[1] = (_Float16)v0.y;
                hv[2] = (_Float16)v0.z; hv[3] = (_Float16)v0.w;
                hv[4] = (_Float16)v1.x; hv[5] = (_Float16)v1.y;
                hv[6] = (_Float16)v1.z; hv[7] = (_Float16)v1.w;
            } else {
                const _Float16* ap = (const _Float16*)rowp[p];
                hv = *(const half8*)&ap[c * 32 + kq * 8];
            }
            *(half8*)&Asm[row * 40 + kq * 8] = hv;
        }
    };

    f32x4 acc[2][8];
#pragma unroll
    for (int rt = 0; rt < 2; ++rt)
#pragma unroll
        for (int ct = 0; ct < 8; ++ct) acc[rt][ct] = (f32x4){0.f, 0.f, 0.f, 0.f};

    constexpr int CH = K / 32;
    stageA(0);
    __syncthreads();
#pragma unroll
    for (int c = 0; c < CH; ++c) {
        half8 a0 = *(const half8*)&Asm[(w * 32 + l15) * 40 + g * 8];
        half8 a1 = *(const half8*)&Asm[(w * 32 + 16 + l15) * 40 + g * 8];
#pragma unroll
        for (int ct = 0; ct < 8; ++ct) {
            half8 b = *(const half8*)&Bsm[(ct * 16 + l15) * BSTR + c * 32 + g * 8];
            acc[0][ct] = __builtin_amdgcn_mfma_f32_16x16x32_f16(a0, b, acc[0][ct], 0, 0, 0);
            acc[1][ct] = __builtin_amdgcn_mfma_f32_16x16x32_f16(a1, b, acc[1][ct], 0, 0, 0);
        }
        __syncthreads();
        if (c + 1 < CH) {
            stageA(c + 1);
            __syncthreads();
        }
    }

#pragma unroll
    for (int rt = 0; rt < 2; ++rt)
#pragma unroll
        for (int reg = 0; reg < 4; ++reg) {
            float s0 = 0.f, s1 = 0.f, d0 = 0.f, d1 = 0.f;
#pragma unroll
            for (int ct = 0; ct < 4; ++ct) {
                float v = acc[rt][ct][reg];
                s0 = fmaf(v, attL[ct * 16 + l15], s0);
                d0 = fmaf(v, attL[128 + ct * 16 + l15], d0);
            }
#pragma unroll
            for (int ct = 4; ct < 8; ++ct) {
                float v = acc[rt][ct][reg];
                s1 = fmaf(v, attL[ct * 16 + l15], s1);
                d1 = fmaf(v, attL[128 + ct * 16 + l15], d1);
            }
#pragma unroll
            for (int o = 1; o < 16; o <<= 1) {
                s0 += __shfl_xor(s0, o); s1 += __shfl_xor(s1, o);
                d0 += __shfl_xor(d0, o); d1 += __shfl_xor(d1, o);
            }
            if (l15 == 0) {
                int row = blkrow + w * 32 + rt * 16 + g * 4 + reg;
                *(float2*)&a_s[row * 2] = make_float2(s0, s1);
                *(float2*)&a_d[row * 2] = make_float2(d0, d1);
            }
        }

#pragma unroll
    for (int rt = 0; rt < 2; ++rt)
#pragma unroll
        for (int ct = 0; ct < 8; ++ct)
#pragma unroll
            for (int reg = 0; reg < 4; ++reg)
                epi[(w * 32 + rt * 16 + g * 4 + reg) * 136 + ct * 16 + l15] =
                    (_Float16)acc[rt][ct][reg];
    __syncthreads();
#pragma unroll
    for (int p = 0; p < 8; ++p) {
        int idx = tid + p * 256;
        int row = idx >> 4, c8 = idx & 15;
        half8 v = *(const half8*)&epi[row * 136 + c8 * 8];
        if (c8 < 8)
            *(half8*)&h0[(size_t)(blkrow + row) * 64 + c8 * 8] = v;
        else
            *(half8*)&h1[(size_t)(blkrow + row) * 64 + (c8 - 8) * 8] = v;
    }
}

// ---------------- GAT aggregation, ONE HEAD per dispatch ----------------
// Gathers from a 10MB per-head table (L2 hit-rate lever). Wave per dst;
// PV: lane = (edge-slot e01 = lane>>5, channel-pair c = lane&31); one
// instruction fetches 2 rows x 128B. Final cross-slot shfl_xor(32) reduce.
// CONCAT pass writes its 64-channel half of x1h; final layer: HEAD 0 writes
// 0.5*r+bias, HEAD 1 accumulates (separate dispatches -> ordered).

template <int HEAD, bool CONCAT>
__global__ __launch_bounds__(256) void gat_agg_head(const __half* __restrict__ hhead,
        const int* __restrict__ row_ptr, const int* __restrict__ src_sorted,
        const float* __restrict__ a_s, const float* __restrict__ a_d,
        const float* __restrict__ bias, void* __restrict__ outv) {
    __shared__ int   s_idx[4][64];
    __shared__ float s_w[4][64];
    int wid   = threadIdx.x >> 6;
    int lane  = threadIdx.x & 63;
    int dnode = blockIdx.x * 4 + wid;
    if (dnode >= N_NODES) return;
    int start = row_ptr[dnode], end = row_ptr[dnode + 1];
    int deg = end - start;
    float adh = a_d[dnode * 2 + HEAD];
    float den = 0.f;
    const __half2* h2 = (const __half2*)hhead;  // [N][32] half2
    const int e01 = lane >> 5;
    const int c   = lane & 31;
    float2 acc = {0.f, 0.f};

    if (deg <= 64) {  // fast path (no max pass: logits are O(0.3), exp safe)
        float wv = 0.f;
        if (lane < deg) {
            int s = src_sorted[start + lane];
            float v = a_s[s * 2 + HEAD] + adh;
            v = v > 0.f ? v : NEG_SLOPE * v;
            wv = __expf(v);
            s_idx[wid][lane] = s;
            s_w[wid][lane]   = wv;
        }
        den = wv;
        for (int o = 32; o; o >>= 1) den += __shfl_xor(den, o);
        int j = 0;
#pragma unroll 1
        for (; j + 8 <= deg; j += 8) {
            int j0 = j + e01, j1 = j + 2 + e01, j2 = j + 4 + e01, j3 = j + 6 + e01;
            int si0 = s_idx[wid][j0], si1 = s_idx[wid][j1];
            int si2 = s_idx[wid][j2], si3 = s_idx[wid][j3];
            float w0 = s_w[wid][j0], w1 = s_w[wid][j1];
            float w2 = s_w[wid][j2], w3 = s_w[wid][j3];
            float2 q0 = __half22float2(h2[(size_t)si0 * 32 + c]);
            float2 q1 = __half22float2(h2[(size_t)si1 * 32 + c]);
            float2 q2 = __half22float2(h2[(size_t)si2 * 32 + c]);
            float2 q3 = __half22float2(h2[(size_t)si3 * 32 + c]);
            acc.x = fmaf(w0, q0.x, acc.x); acc.y = fmaf(w0, q0.y, acc.y);
            acc.x = fmaf(w1, q1.x, acc.x); acc.y = fmaf(w1, q1.y, acc.y);
            acc.x = fmaf(w2, q2.x, acc.x); acc.y = fmaf(w2, q2.y, acc.y);
            acc.x = fmaf(w3, q3.x, acc.x); acc.y = fmaf(w3, q3.y, acc.y);
        }
        for (; j < deg; j += 2) {
            int jj = j + e01;
            bool val = jj < deg;
            int   si = s_idx[wid][val ? jj : 0];
            float w  = val ? s_w[wid][jj] : 0.f;
            float2 q = __half22float2(h2[(size_t)si * 32 + c]);
            acc.x = fmaf(w, q.x, acc.x);
            acc.y = fmaf(w, q.y, acc.y);
        }
    } else {  // general path (vanishingly rare for Poisson(16))
        for (int c0 = start; c0 < end; c0 += 64) {
            int len = min(64, end - c0);
            if (lane < len) {
                int s = src_sorted[c0 + lane];
                float v = a_s[s * 2 + HEAD] + adh;
                v = v > 0.f ? v : NEG_SLOPE * v;
                float wv = __expf(v);
                den += wv;
                s_idx[wid][lane] = s;
                s_w[wid][lane]   = wv;
            }
            __builtin_amdgcn_wave_barrier();
            for (int j = 0; j < len; j += 2) {
                int jj = j + e01;
                bool val = jj < len;
                int   si = s_idx[wid][val ? jj : 0];
                float w  = val ? s_w[wid][jj] : 0.f;
                float2 q = __half22float2(h2[(size_t)si * 32 + c]);
                acc.x = fmaf(w, q.x, acc.x);
                acc.y = fmaf(w, q.y, acc.y);
            }
            __builtin_amdgcn_wave_barrier();
        }
        for (int o = 32; o; o >>= 1) den += __shfl_xor(den, o);
    }

    acc.x += __shfl_xor(acc.x, 32);
    acc.y += __shfl_xor(acc.y, 32);
    float inv = 1.f / (den + 1e-16f);
    float2 r = {acc.x * inv, acc.y * inv};

    if (lane < 32) {
        if (CONCAT) {
            __half* out = (__half*)outv;
            float2 b = *(const float2*)(bias + HEAD * 64 + c * 2);
            *(__half2*)(out + (size_t)dnode * 128 + HEAD * 64 + c * 2) =
                __floats2half2_rn(r.x + b.x, r.y + b.y);
        } else {
            float* out = (float*)outv;
            if (HEAD == 0) {
                float2 b = *(const float2*)(bias + c * 2);
                float2 o2 = {0.5f * r.x + b.x, 0.5f * r.y + b.y};
                *(float2*)(out + (size_t)dnode * 64 + c * 2) = o2;
            } else {
                float2 cur = *(float2*)(out + (size_t)dnode * 64 + c * 2);
                float2 o2 = {cur.x + 0.5f * r.x, cur.y + 0.5f * r.y};
                *(float2*)(out + (size_t)dnode * 64 + c * 2) = o2;
            }
        }
    }
}

// ---------------- final pair dot ----------------

__global__ void pair_dot_kernel(const float* __restrict__ emb, const int* __restrict__ ui,
                                const int* __restrict__ ii, float* __restrict__ out, int B) {
    int w    = blockIdx.x * 4 + (threadIdx.x >> 6);
    int lane = threadIdx.x & 63;
    if (w >= B) return;
    float a = emb[(size_t)ui[w] * 64 + lane];
    float b = emb[(size_t)(NU_NODES + ii[w]) * 64 + lane];
    float p = a * b;
    for (int o = 32; o; o >>= 1) p += __shfl_xor(p, o);
    if (lane == 0) out[w] = p;
}

extern "C" void kernel_launch(void* const* d_in, const int* in_sizes, int n_in,
                              void* d_out, int out_size, void* d_ws, size_t ws_size,
                              hipStream_t stream) {
    const float* Gu       = (const float*)d_in[0];
    const float* Gi       = (const float*)d_in[1];
    const float* W0       = (const float*)d_in[2];
    const float* att_src0 = (const float*)d_in[3];
    const float* att_dst0 = (const float*)d_in[4];
    const float* b0       = (const float*)d_in[5];
    const float* W1       = (const float*)d_in[6];
    const float* att_src1 = (const float*)d_in[7];
    const float* att_dst1 = (const float*)d_in[8];
    const float* b1       = (const float*)d_in[9];
    const int* edge_index = (const int*)d_in[10];
    const int* user_idx   = (const int*)d_in[11];
    const int* item_idx   = (const int*)d_in[12];
    float* outp           = (float*)d_out;

    const int N = N_NODES, E = E_EDGES;
    char* wsp = (char*)d_ws;
    auto alloc = [&](size_t bytes) {
        void* p = wsp;
        wsp += (bytes + 255) & ~(size_t)255;
        return p;
    };
    float*  emb = (float*)alloc((size_t)N * 64 * 4);    // final embeddings (f32)
    __half* h0  = (__half*)alloc((size_t)N * 64 * 2);   // head-0 table (10MB)
    __half* h1  = (__half*)alloc((size_t)N * 64 * 2);   // head-1 table (10MB)
    __half* x1h = (__half*)alloc((size_t)N * 128 * 2);  // layer0 output (fp16, concat)
    float*  a_s = (float*)alloc((size_t)N * 2 * 4);
    float*  a_d = (float*)alloc((size_t)N * 2 * 4);
    int* row_ptr    = (int*)alloc((size_t)(N + 1) * 4);
    int* counts     = (int*)alloc((size_t)N * 4);
    int* bsums      = (int*)alloc(512 * 4);
    int* src_sorted = (int*)alloc((size_t)E * 4);
    int* bucket_ptr  = (int*)alloc((NBUCK + 1) * 4);
    int* gfill       = (int*)alloc((NBUCK + 1) * 4);
    // pk only lives during CSR build; x1h only written after -> overlay
    unsigned long long* pk = (unsigned long long*)x1h;

    const int* esrc = edge_index;
    const int* edst = edge_index + E;

    // row_ptr: exact-dst histogram + per-bucket scan + top scan + fixup
    hipMemsetAsync(counts, 0, (size_t)N * 4, stream);
    hist_kernel<<<E / 256, 256, 0, stream>>>(edst, counts, E);
    scan256_kernel<<<NBUCK, 256, 0, stream>>>(counts, row_ptr, bsums);
    topscan_kernel<<<1, 512, 0, stream>>>(bsums, bucket_ptr, gfill);
    fixup_kernel<<<NBUCK, 256, 0, stream>>>(row_ptr, bucket_ptr);

    // binned scatter -> src_sorted (CSR adjacency by dst)
    bscatter_kernel<<<(E + SCHUNK - 1) / SCHUNK, 512, 0, stream>>>(esrc, edst, gfill, pk, E);
    escatter_kernel<<<NBUCK, 256, 0, stream>>>(pk, bucket_ptr, row_ptr, src_sorted);

    // layer 0
    gemm_mfma<64, true><<<N / 128, 256, 0, stream>>>(Gu, Gi, NU_NODES, W0, att_src0, att_dst0,
                                                     h0, h1, a_s, a_d);
    gat_agg_head<0, true><<<(N + 3) / 4, 256, 0, stream>>>(h0, row_ptr, src_sorted, a_s, a_d,
                                                           b0, x1h);
    gat_agg_head<1, true><<<(N + 3) / 4, 256, 0, stream>>>(h1, row_ptr, src_sorted, a_s, a_d,
                                                           b0, x1h);

    // layer 1
    gemm_mfma<128, false><<<N / 128, 256, 0, stream>>>(x1h, x1h, N, W1, att_src1, att_dst1,
                                                       h0, h1, a_s, a_d);
    gat_agg_head<0, false><<<(N + 3) / 4, 256, 0, stream>>>(h0, row_ptr, src_sorted, a_s, a_d,
                                                            b1, emb);
    gat_agg_head<1, false><<<(N + 3) / 4, 256, 0, stream>>>(h1, row_ptr, src_sorted, a_s, a_d,
                                                            b1, emb);

    // final dot
    pair_dot_kernel<<<B_PAIRS / 4, 256, 0, stream>>>(emb, user_idx, item_idx, outp, B_PAIRS);
}

// Round 12
// 224.534 us; speedup vs baseline: 1.3943x; 1.3943x over previous
//
#include <hip/hip_runtime.h>
#include <hip/hip_fp16.h>
#include <math.h>

#define N_NODES   80000
#define NU_NODES  40000
#define E_EDGES   1280000
#define B_PAIRS   8192
#define NEG_SLOPE 0.2f
#define NBUCK     313   // ceil(N_NODES / 256)
#define SCHUNK    2048  // edges per binning block

typedef _Float16 half8 __attribute__((ext_vector_type(8)));
typedef float    f32x4 __attribute__((ext_vector_type(4)));

// ---------------- CSR build: coarse hist -> scan -> binned scatter ----------------
// No per-node global histogram: row_ptr is derived per bucket inside escatter2.

__global__ __launch_bounds__(512) void bhist313_kernel(const int* __restrict__ dst,
                                                       int* __restrict__ bucketCount, int E) {
    __shared__ int histL[NBUCK];
    for (int i = threadIdx.x; i < NBUCK; i += 512) histL[i] = 0;
    __syncthreads();
    int base = blockIdx.x * SCHUNK;
#pragma unroll
    for (int r = 0; r < SCHUNK / 512; ++r) {
        int e = base + r * 512 + threadIdx.x;
        if (e < E) atomicAdd(&histL[dst[e] >> 8], 1);
    }
    __syncthreads();
    for (int i = threadIdx.x; i < NBUCK; i += 512)
        if (histL[i]) atomicAdd(&bucketCount[i], histL[i]);
}

__global__ __launch_bounds__(512) void topscan_kernel(const int* __restrict__ bucketCount,
                                                      int* __restrict__ bucket_ptr,
                                                      int* __restrict__ gfill) {
    __shared__ int tmp[512];
    int t = threadIdx.x;
    int v = (t < NBUCK) ? bucketCount[t] : 0;
    tmp[t] = v;
    __syncthreads();
    for (int off = 1; off < 512; off <<= 1) {
        int x = (t >= off) ? tmp[t - off] : 0;
        __syncthreads();
        tmp[t] += x;
        __syncthreads();
    }
    int excl = tmp[t] - v;
    if (t < NBUCK) {
        bucket_ptr[t] = excl;
        gfill[t]      = excl;
        if (t == NBUCK - 1) bucket_ptr[NBUCK] = excl + v;
    }
}

__global__ __launch_bounds__(512) void bscatter_kernel(const int* __restrict__ src,
                                                       const int* __restrict__ dst,
                                                       int* __restrict__ gfill,
                                                       unsigned long long* __restrict__ pk,
                                                       int E) {
    __shared__ int histL[NBUCK];
    __shared__ int baseL[NBUCK];
    __shared__ int rankL[NBUCK];
    for (int i = threadIdx.x; i < NBUCK; i += 512) { histL[i] = 0; rankL[i] = 0; }
    __syncthreads();
    int base = blockIdx.x * SCHUNK;
#pragma unroll
    for (int r = 0; r < SCHUNK / 512; ++r) {
        int e = base + r * 512 + threadIdx.x;
        if (e < E) atomicAdd(&histL[dst[e] >> 8], 1);
    }
    __syncthreads();
    for (int i = threadIdx.x; i < NBUCK; i += 512)
        baseL[i] = histL[i] ? atomicAdd(&gfill[i], histL[i]) : 0;
    __syncthreads();
#pragma unroll
    for (int r = 0; r < SCHUNK / 512; ++r) {
        int e = base + r * 512 + threadIdx.x;
        if (e < E) {
            int d = dst[e];
            int b = d >> 8;
            int rk = atomicAdd(&rankL[b], 1);
            pk[baseL[b] + rk] = ((unsigned long long)(unsigned)d << 32) | (unsigned)src[e];
        }
    }
}

// Per bucket: count 256 node bins in LDS -> in-block scan -> write row_ptr
// -> exact scatter. All writes for a node's list from one block.
__global__ __launch_bounds__(256) void escatter2_kernel(
        const unsigned long long* __restrict__ pk, const int* __restrict__ bucket_ptr,
        int* __restrict__ row_ptr, int* __restrict__ src_sorted) {
    __shared__ int cntL[256];
    __shared__ int tmp[256];
    __shared__ int rpL[256];
    int b = blockIdx.x;
    int t = threadIdx.x;
    int node0 = b << 8;
    int s = bucket_ptr[b], e = bucket_ptr[b + 1];
    cntL[t] = 0;
    __syncthreads();
    for (int k = s + t; k < e; k += 256) atomicAdd(&cntL[(int)(pk[k] >> 32) & 255], 1);
    __syncthreads();
    int v = cntL[t];
    tmp[t] = v;
    __syncthreads();
    for (int off = 1; off < 256; off <<= 1) {
        int x = (t >= off) ? tmp[t - off] : 0;
        __syncthreads();
        tmp[t] += x;
        __syncthreads();
    }
    int excl = tmp[t] - v;
    rpL[t] = s + excl;
    int node = node0 + t;
    if (node < N_NODES) row_ptr[node] = s + excl;
    if (b == NBUCK - 1 && t == 0) row_ptr[N_NODES] = e;
    cntL[t] = 0;
    __syncthreads();
    for (int k = s + t; k < e; k += 256) {
        unsigned long long p = pk[k];
        int lo = (int)(p >> 32) & 255;
        int pos = atomicAdd(&cntL[lo], 1);
        src_sorted[rpL[lo] + pos] = (int)(unsigned)p;
    }
}

// ---------------- MFMA f16 GEMM + fused attention-dot epilogue ----------------

template <int K, bool AF32>
__global__ __launch_bounds__(256) void gemm_mfma(const void* __restrict__ A0v,
                                                 const void* __restrict__ A1v, int split,
                                                 const float* __restrict__ W,
                                                 const float* __restrict__ attS,
                                                 const float* __restrict__ attD,
                                                 __half* __restrict__ hh,
                                                 float* __restrict__ a_s,
                                                 float* __restrict__ a_d) {
    constexpr int BSTR   = K + 8;
    constexpr int BSM_SZ = 128 * BSTR * 2;
    constexpr int EPI_SZ = 128 * 136 * 2;
    constexpr int ATT_OFF = (10240 + BSM_SZ > EPI_SZ) ? (10240 + BSM_SZ) : EPI_SZ;
    __shared__ __align__(16) char lds[ATT_OFF + 1024];
    _Float16* Asm  = (_Float16*)lds;
    _Float16* Bsm  = (_Float16*)(lds + 10240);
    _Float16* epi  = (_Float16*)lds;
    float*    attL = (float*)(lds + ATT_OFF);

    const int tid    = threadIdx.x;
    const int w      = tid >> 6;
    const int l      = tid & 63;
    const int l15    = l & 15;
    const int g      = l >> 4;
    const int blkrow = blockIdx.x * 128;

    attL[tid] = (tid < 128) ? attS[tid] : attD[tid - 128];

    for (int idx = tid; idx < K * 32; idx += 256) {
        int k = idx >> 5, c4 = idx & 31;
        float4 wv = *(const float4*)&W[(size_t)k * 128 + c4 * 4];
        Bsm[(c4 * 4 + 0) * BSTR + k] = (_Float16)wv.x;
        Bsm[(c4 * 4 + 1) * BSTR + k] = (_Float16)wv.y;
        Bsm[(c4 * 4 + 2) * BSTR + k] = (_Float16)wv.z;
        Bsm[(c4 * 4 + 3) * BSTR + k] = (_Float16)wv.w;
    }

    const void* rowp[2];
#pragma unroll
    for (int p = 0; p < 2; ++p) {
        int idx = tid + p * 256;
        int row = idx >> 2;
        int grow = blkrow + row;
        if (AF32) {
            const float* A0 = (const float*)A0v;
            const float* A1 = (const float*)A1v;
            rowp[p] = (grow < split) ? (const void*)(A0 + (size_t)grow * K)
                                     : (const void*)(A1 + (size_t)(grow - split) * K);
        } else {
            rowp[p] = (const void*)((const _Float16*)A0v + (size_t)grow * K);
        }
    }

    auto stageA = [&](int c) {
#pragma unroll
        for (int p = 0; p < 2; ++p) {
            int idx = tid + p * 256;
            int row = idx >> 2, kq = idx & 3;
            half8 hv;
            if (AF32) {
                const float* ap = (const float*)rowp[p];
                float4 v0 = *(const float4*)&ap[c * 32 + kq * 8];
                float4 v1 = *(const float4*)&ap[c * 32 + kq * 8 + 4];
                hv[0] = (_Float16)v0.x; hv[1] = (_Float16)v0.y;
                hv[2] = (_Float16)v0.z; hv[3] = (_Float16)v0.w;
                hv[4] = (_Float16)v1.x; hv[5] = (_Float16)v1.y;
                hv[6] = (_Float16)v1.z; hv[7] = (_Float16)v1.w;
            } else {
                const _Float16* ap = (const _Float16*)rowp[p];
                hv = *(const half8*)&ap[c * 32 + kq * 8];
            }
            *(half8*)&Asm[row * 40 + kq * 8] = hv;
        }
    };

    f32x4 acc[2][8];
#pragma unroll
    for (int rt = 0; rt < 2; ++rt)
#pragma unroll
        for (int ct = 0; ct < 8; ++ct) acc[rt][ct] = (f32x4){0.f, 0.f, 0.f, 0.f};

    constexpr int CH = K / 32;
    stageA(0);
    __syncthreads();
#pragma unroll
    for (int c = 0; c < CH; ++c) {
        half8 a0 = *(const half8*)&Asm[(w * 32 + l15) * 40 + g * 8];
        half8 a1 = *(const half8*)&Asm[(w * 32 + 16 + l15) * 40 + g * 8];
#pragma unroll
        for (int ct = 0; ct < 8; ++ct) {
            half8 b = *(const half8*)&Bsm[(ct * 16 + l15) * BSTR + c * 32 + g * 8];
            acc[0][ct] = __builtin_amdgcn_mfma_f32_16x16x32_f16(a0, b, acc[0][ct], 0, 0, 0);
            acc[1][ct] = __builtin_amdgcn_mfma_f32_16x16x32_f16(a1, b, acc[1][ct], 0, 0, 0);
        }
        __syncthreads();
        if (c + 1 < CH) {
            stageA(c + 1);
            __syncthreads();
        }
    }

#pragma unroll
    for (int rt = 0; rt < 2; ++rt)
#pragma unroll
        for (int reg = 0; reg < 4; ++reg) {
            float s0 = 0.f, s1 = 0.f, d0 = 0.f, d1 = 0.f;
#pragma unroll
            for (int ct = 0; ct < 4; ++ct) {
                float v = acc[rt][ct][reg];
                s0 = fmaf(v, attL[ct * 16 + l15], s0);
                d0 = fmaf(v, attL[128 + ct * 16 + l15], d0);
            }
#pragma unroll
            for (int ct = 4; ct < 8; ++ct) {
                float v = acc[rt][ct][reg];
                s1 = fmaf(v, attL[ct * 16 + l15], s1);
                d1 = fmaf(v, attL[128 + ct * 16 + l15], d1);
            }
#pragma unroll
            for (int o = 1; o < 16; o <<= 1) {
                s0 += __shfl_xor(s0, o); s1 += __shfl_xor(s1, o);
                d0 += __shfl_xor(d0, o); d1 += __shfl_xor(d1, o);
            }
            if (l15 == 0) {
                int row = blkrow + w * 32 + rt * 16 + g * 4 + reg;
                *(float2*)&a_s[row * 2] = make_float2(s0, s1);
                *(float2*)&a_d[row * 2] = make_float2(d0, d1);
            }
        }

#pragma unroll
    for (int rt = 0; rt < 2; ++rt)
#pragma unroll
        for (int ct = 0; ct < 8; ++ct)
#pragma unroll
            for (int reg = 0; reg < 4; ++reg)
                epi[(w * 32 + rt * 16 + g * 4 + reg) * 136 + ct * 16 + l15] =
                    (_Float16)acc[rt][ct][reg];
    __syncthreads();
#pragma unroll
    for (int p = 0; p < 8; ++p) {
        int idx = tid + p * 256;
        int row = idx >> 4, c8 = idx & 15;
        *(half8*)&hh[(size_t)(blkrow + row) * 128 + c8 * 8] =
            *(const half8*)&epi[row * 136 + c8 * 8];
    }
}

// ---------------- GAT aggregation: one WAVE per dst node, both heads ----------------
// R8-benched structure (60us): LDS-staged softmax results, j-loop unroll x4.
// Max pass deleted (logits O(0.3); exp direct; verified absmax-neutral R10/R11).

template <bool CONCAT>
__global__ __launch_bounds__(256) void gat_agg_kernel(const __half* __restrict__ hh,
        const int* __restrict__ row_ptr, const int* __restrict__ src_sorted,
        const float* __restrict__ a_s, const float* __restrict__ a_d,
        const float* __restrict__ bias, void* __restrict__ outv) {
    __shared__ int   s_idx[4][64];
    __shared__ float s_w[4][64][2];
    int wid   = threadIdx.x >> 6;
    int lane  = threadIdx.x & 63;
    int dnode = blockIdx.x * 4 + wid;
    if (dnode >= N_NODES) return;
    int start = row_ptr[dnode], end = row_ptr[dnode + 1];
    int deg = end - start;
    float2 ad = *(const float2*)(a_d + dnode * 2);
    int hh_head = lane >> 5;
    float2 acc = {0.f, 0.f};
    float den0 = 0.f, den1 = 0.f;
    const __half2* h2 = (const __half2*)hh;

    if (deg <= 64) {  // fast path
        if (lane < deg) {
            int s = src_sorted[start + lane];
            float2 as = *(const float2*)(a_s + s * 2);
            float v0 = as.x + ad.x; v0 = v0 > 0.f ? v0 : NEG_SLOPE * v0;
            float v1 = as.y + ad.y; v1 = v1 > 0.f ? v1 : NEG_SLOPE * v1;
            float w0 = __expf(v0), w1 = __expf(v1);
            den0 = w0; den1 = w1;
            s_idx[wid][lane] = s;
            s_w[wid][lane][0] = w0;
            s_w[wid][lane][1] = w1;
        }
        for (int o = 32; o; o >>= 1) {
            den0 += __shfl_xor(den0, o);
            den1 += __shfl_xor(den1, o);
        }
        int j = 0;
#pragma unroll 1
        for (; j + 4 <= deg; j += 4) {
            int   si0 = s_idx[wid][j + 0], si1 = s_idx[wid][j + 1];
            int   si2 = s_idx[wid][j + 2], si3 = s_idx[wid][j + 3];
            float w0 = s_w[wid][j + 0][hh_head], w1 = s_w[wid][j + 1][hh_head];
            float w2 = s_w[wid][j + 2][hh_head], w3 = s_w[wid][j + 3][hh_head];
            float2 q0 = __half22float2(h2[(size_t)si0 * 64 + lane]);
            float2 q1 = __half22float2(h2[(size_t)si1 * 64 + lane]);
            float2 q2 = __half22float2(h2[(size_t)si2 * 64 + lane]);
            float2 q3 = __half22float2(h2[(size_t)si3 * 64 + lane]);
            acc.x = fmaf(w0, q0.x, acc.x); acc.y = fmaf(w0, q0.y, acc.y);
            acc.x = fmaf(w1, q1.x, acc.x); acc.y = fmaf(w1, q1.y, acc.y);
            acc.x = fmaf(w2, q2.x, acc.x); acc.y = fmaf(w2, q2.y, acc.y);
            acc.x = fmaf(w3, q3.x, acc.x); acc.y = fmaf(w3, q3.y, acc.y);
        }
        for (; j < deg; ++j) {
            int  si = s_idx[wid][j];
            float w = s_w[wid][j][hh_head];
            float2 v = __half22float2(h2[(size_t)si * 64 + lane]);
            acc.x = fmaf(w, v.x, acc.x);
            acc.y = fmaf(w, v.y, acc.y);
        }
    } else {  // general path (vanishingly rare for Poisson(16))
        for (int c0 = start; c0 < end; c0 += 64) {
            int len = min(64, end - c0);
            if (lane < len) {
                int s = src_sorted[c0 + lane];
                float2 as = *(const float2*)(a_s + s * 2);
                float v0 = as.x + ad.x; v0 = v0 > 0.f ? v0 : NEG_SLOPE * v0;
                float v1 = as.y + ad.y; v1 = v1 > 0.f ? v1 : NEG_SLOPE * v1;
                float w0 = __expf(v0), w1 = __expf(v1);
                den0 += w0; den1 += w1;
                s_idx[wid][lane] = s;
                s_w[wid][lane][0] = w0;
                s_w[wid][lane][1] = w1;
            }
            for (int j = 0; j < len; ++j) {
                int  si = s_idx[wid][j];
                float w = s_w[wid][j][hh_head];
                float2 v = __half22float2(h2[(size_t)si * 64 + lane]);
                acc.x = fmaf(w, v.x, acc.x);
                acc.y = fmaf(w, v.y, acc.y);
            }
        }
        for (int o = 32; o; o >>= 1) {
            den0 += __shfl_xor(den0, o);
            den1 += __shfl_xor(den1, o);
        }
    }

    float inv = 1.f / ((hh_head ? den1 : den0) + 1e-16f);
    float2 r = {acc.x * inv, acc.y * inv};

    if (CONCAT) {
        __half* out = (__half*)outv;
        float2 b = *(const float2*)(bias + lane * 2);
        __half2 o2 = __floats2half2_rn(r.x + b.x, r.y + b.y);
        *(__half2*)(out + (size_t)dnode * 128 + lane * 2) = o2;
    } else {
        float* out = (float*)outv;
        float ox = __shfl_xor(r.x, 32);
        float oy = __shfl_xor(r.y, 32);
        if (lane < 32) {
            float2 b = *(const float2*)(bias + lane * 2);
            float2 o2 = {0.5f * (r.x + ox) + b.x, 0.5f * (r.y + oy) + b.y};
            *(float2*)(out + (size_t)dnode * 64 + lane * 2) = o2;
        }
    }
}

// ---------------- final pair dot ----------------

__global__ void pair_dot_kernel(const float* __restrict__ emb, const int* __restrict__ ui,
                                const int* __restrict__ ii, float* __restrict__ out, int B) {
    int w    = blockIdx.x * 4 + (threadIdx.x >> 6);
    int lane = threadIdx.x & 63;
    if (w >= B) return;
    float a = emb[(size_t)ui[w] * 64 + lane];
    float b = emb[(size_t)(NU_NODES + ii[w]) * 64 + lane];
    float p = a * b;
    for (int o = 32; o; o >>= 1) p += __shfl_xor(p, o);
    if (lane == 0) out[w] = p;
}

extern "C" void kernel_launch(void* const* d_in, const int* in_sizes, int n_in,
                              void* d_out, int out_size, void* d_ws, size_t ws_size,
                              hipStream_t stream) {
    const float* Gu       = (const float*)d_in[0];
    const float* Gi       = (const float*)d_in[1];
    const float* W0       = (const float*)d_in[2];
    const float* att_src0 = (const float*)d_in[3];
    const float* att_dst0 = (const float*)d_in[4];
    const float* b0       = (const float*)d_in[5];
    const float* W1       = (const float*)d_in[6];
    const float* att_src1 = (const float*)d_in[7];
    const float* att_dst1 = (const float*)d_in[8];
    const float* b1       = (const float*)d_in[9];
    const int* edge_index = (const int*)d_in[10];
    const int* user_idx   = (const int*)d_in[11];
    const int* item_idx   = (const int*)d_in[12];
    float* outp           = (float*)d_out;

    const int N = N_NODES, E = E_EDGES;
    char* wsp = (char*)d_ws;
    auto alloc = [&](size_t bytes) {
        void* p = wsp;
        wsp += (bytes + 255) & ~(size_t)255;
        return p;
    };
    float*  emb = (float*)alloc((size_t)N * 64 * 4);    // final embeddings (f32)
    __half* hh  = (__half*)alloc((size_t)N * 128 * 2);  // fp16 h (both layers)
    __half* x1h = (__half*)alloc((size_t)N * 128 * 2);  // layer0 output (fp16)
    float*  a_s = (float*)alloc((size_t)N * 2 * 4);
    float*  a_d = (float*)alloc((size_t)N * 2 * 4);
    int* row_ptr     = (int*)alloc((size_t)(N + 1) * 4);
    int* src_sorted  = (int*)alloc((size_t)E * 4);
    int* bucketCount = (int*)alloc((NBUCK + 1) * 4);
    int* bucket_ptr  = (int*)alloc((NBUCK + 1) * 4);
    int* gfill       = (int*)alloc((NBUCK + 1) * 4);
    // pk only lives during CSR build; x1h only written after -> overlay
    unsigned long long* pk = (unsigned long long*)x1h;

    const int* esrc = edge_index;
    const int* edst = edge_index + E;

    // CSR build: coarse hist -> scan -> binned scatter (row_ptr derived in escatter2)
    hipMemsetAsync(bucketCount, 0, (NBUCK + 1) * 4, stream);
    int nblk = (E + SCHUNK - 1) / SCHUNK;
    bhist313_kernel<<<nblk, 512, 0, stream>>>(edst, bucketCount, E);
    topscan_kernel<<<1, 512, 0, stream>>>(bucketCount, bucket_ptr, gfill);
    bscatter_kernel<<<nblk, 512, 0, stream>>>(esrc, edst, gfill, pk, E);
    escatter2_kernel<<<NBUCK, 256, 0, stream>>>(pk, bucket_ptr, row_ptr, src_sorted);

    // layer 0: MFMA GEMM (f32 inputs cast to f16) + fused att dots
    gemm_mfma<64, true><<<N / 128, 256, 0, stream>>>(Gu, Gi, NU_NODES, W0, att_src0, att_dst0,
                                                     hh, a_s, a_d);
    gat_agg_kernel<true><<<(N + 3) / 4, 256, 0, stream>>>(hh, row_ptr, src_sorted, a_s, a_d,
                                                          b0, x1h);

    // layer 1: MFMA GEMM (fp16 input)
    gemm_mfma<128, false><<<N / 128, 256, 0, stream>>>(x1h, x1h, N, W1, att_src1, att_dst1,
                                                       hh, a_s, a_d);
    gat_agg_kernel<false><<<(N + 3) / 4, 256, 0, stream>>>(hh, row_ptr, src_sorted, a_s, a_d,
                                                           b1, emb);

    // final dot
    pair_dot_kernel<<<B_PAIRS / 4, 256, 0, stream>>>(emb, user_idx, item_idx, outp, B_PAIRS);
}

// Round 13
// 222.353 us; speedup vs baseline: 1.4079x; 1.0098x over previous
//
#include <hip/hip_runtime.h>
#include <hip/hip_fp16.h>
#include <math.h>

#define N_NODES   80000
#define NU_NODES  40000
#define E_EDGES   1280000
#define B_PAIRS   8192
#define NEG_SLOPE 0.2f
#define NBUCK     313   // ceil(N_NODES / 256)
#define SCHUNK    2048  // edges per binning block

typedef _Float16 half8 __attribute__((ext_vector_type(8)));
typedef float    f32x4 __attribute__((ext_vector_type(4)));

// ---------------- CSR build ----------------
// bucket histogram is fused into gemm_mfma<64> (HIST=true). Then:
// topscan -> bscatter -> escatter2 (derives row_ptr per bucket).

__global__ __launch_bounds__(512) void topscan_kernel(const int* __restrict__ bucketCount,
                                                      int* __restrict__ bucket_ptr,
                                                      int* __restrict__ gfill) {
    __shared__ int tmp[512];
    int t = threadIdx.x;
    int v = (t < NBUCK) ? bucketCount[t] : 0;
    tmp[t] = v;
    __syncthreads();
    for (int off = 1; off < 512; off <<= 1) {
        int x = (t >= off) ? tmp[t - off] : 0;
        __syncthreads();
        tmp[t] += x;
        __syncthreads();
    }
    int excl = tmp[t] - v;
    if (t < NBUCK) {
        bucket_ptr[t] = excl;
        gfill[t]      = excl;
        if (t == NBUCK - 1) bucket_ptr[NBUCK] = excl + v;
    }
}

__global__ __launch_bounds__(512) void bscatter_kernel(const int* __restrict__ src,
                                                       const int* __restrict__ dst,
                                                       int* __restrict__ gfill,
                                                       unsigned long long* __restrict__ pk,
                                                       int E) {
    __shared__ int histL[NBUCK];
    __shared__ int baseL[NBUCK];
    __shared__ int rankL[NBUCK];
    for (int i = threadIdx.x; i < NBUCK; i += 512) { histL[i] = 0; rankL[i] = 0; }
    __syncthreads();
    int base = blockIdx.x * SCHUNK;
#pragma unroll
    for (int r = 0; r < SCHUNK / 512; ++r) {
        int e = base + r * 512 + threadIdx.x;
        if (e < E) atomicAdd(&histL[dst[e] >> 8], 1);
    }
    __syncthreads();
    for (int i = threadIdx.x; i < NBUCK; i += 512)
        baseL[i] = histL[i] ? atomicAdd(&gfill[i], histL[i]) : 0;
    __syncthreads();
#pragma unroll
    for (int r = 0; r < SCHUNK / 512; ++r) {
        int e = base + r * 512 + threadIdx.x;
        if (e < E) {
            int d = dst[e];
            int b = d >> 8;
            int rk = atomicAdd(&rankL[b], 1);
            pk[baseL[b] + rk] = ((unsigned long long)(unsigned)d << 32) | (unsigned)src[e];
        }
    }
}

__global__ __launch_bounds__(256) void escatter2_kernel(
        const unsigned long long* __restrict__ pk, const int* __restrict__ bucket_ptr,
        int* __restrict__ row_ptr, int* __restrict__ src_sorted) {
    __shared__ int cntL[256];
    __shared__ int tmp[256];
    __shared__ int rpL[256];
    int b = blockIdx.x;
    int t = threadIdx.x;
    int node0 = b << 8;
    int s = bucket_ptr[b], e = bucket_ptr[b + 1];
    cntL[t] = 0;
    __syncthreads();
    for (int k = s + t; k < e; k += 256) atomicAdd(&cntL[(int)(pk[k] >> 32) & 255], 1);
    __syncthreads();
    int v = cntL[t];
    tmp[t] = v;
    __syncthreads();
    for (int off = 1; off < 256; off <<= 1) {
        int x = (t >= off) ? tmp[t - off] : 0;
        __syncthreads();
        tmp[t] += x;
        __syncthreads();
    }
    int excl = tmp[t] - v;
    rpL[t] = s + excl;
    int node = node0 + t;
    if (node < N_NODES) row_ptr[node] = s + excl;
    if (b == NBUCK - 1 && t == 0) row_ptr[N_NODES] = e;
    cntL[t] = 0;
    __syncthreads();
    for (int k = s + t; k < e; k += 256) {
        unsigned long long p = pk[k];
        int lo = (int)(p >> 32) & 255;
        int pos = atomicAdd(&cntL[lo], 1);
        src_sorted[rpL[lo] + pos] = (int)(unsigned)p;
    }
}

// ---------------- MFMA f16 GEMM + fused att-dot epilogue (+optional edge hist) ----
// Register-prefetch pipeline: chunk c+1's global A loads issue before chunk c's
// MFMAs (T14); LDS write lands after the post-MFMA barrier. HIST=true blocks
// additionally histogram their 2048-edge chunk first (overlaps with GEMM).

template <int K, bool AF32, bool HIST>
__global__ __launch_bounds__(256) void gemm_mfma(const void* __restrict__ A0v,
                                                 const void* __restrict__ A1v, int split,
                                                 const float* __restrict__ W,
                                                 const float* __restrict__ attS,
                                                 const float* __restrict__ attD,
                                                 __half* __restrict__ hh,
                                                 float* __restrict__ a_s,
                                                 float* __restrict__ a_d,
                                                 const int* __restrict__ edst,
                                                 int* __restrict__ bucketCount) {
    constexpr int BSTR   = K + 8;
    constexpr int BSM_SZ = 128 * BSTR * 2;
    constexpr int EPI_SZ = 128 * 136 * 2;
    constexpr int ATT_OFF = (10240 + BSM_SZ > EPI_SZ) ? (10240 + BSM_SZ) : EPI_SZ;
    __shared__ __align__(16) char lds[ATT_OFF + 1024 + (HIST ? (NBUCK + 7) * 4 : 4)];
    _Float16* Asm  = (_Float16*)lds;
    _Float16* Bsm  = (_Float16*)(lds + 10240);
    _Float16* epi  = (_Float16*)lds;
    float*    attL = (float*)(lds + ATT_OFF);
    int*      histL = (int*)(lds + ATT_OFF + 1024);

    const int tid    = threadIdx.x;
    const int w      = tid >> 6;
    const int l      = tid & 63;
    const int l15    = l & 15;
    const int g      = l >> 4;
    const int blkrow = blockIdx.x * 128;

    if (HIST) {  // fused coarse edge histogram (this block's 2048-edge chunk)
        for (int i = tid; i < NBUCK; i += 256) histL[i] = 0;
        __syncthreads();
        int base = blockIdx.x * SCHUNK;
#pragma unroll
        for (int r = 0; r < SCHUNK / 256; ++r)
            atomicAdd(&histL[edst[base + r * 256 + tid] >> 8], 1);
        __syncthreads();
        for (int i = tid; i < NBUCK; i += 256)
            if (histL[i]) atomicAdd(&bucketCount[i], histL[i]);
        // global atomics drain under the GEMM below; no further sync needed
    }

    attL[tid] = (tid < 128) ? attS[tid] : attD[tid - 128];

    for (int idx = tid; idx < K * 32; idx += 256) {
        int k = idx >> 5, c4 = idx & 31;
        float4 wv = *(const float4*)&W[(size_t)k * 128 + c4 * 4];
        Bsm[(c4 * 4 + 0) * BSTR + k] = (_Float16)wv.x;
        Bsm[(c4 * 4 + 1) * BSTR + k] = (_Float16)wv.y;
        Bsm[(c4 * 4 + 2) * BSTR + k] = (_Float16)wv.z;
        Bsm[(c4 * 4 + 3) * BSTR + k] = (_Float16)wv.w;
    }

    const void* rowp[2];
#pragma unroll
    for (int p = 0; p < 2; ++p) {
        int idx = tid + p * 256;
        int row = idx >> 2;
        int grow = blkrow + row;
        if (AF32) {
            const float* A0 = (const float*)A0v;
            const float* A1 = (const float*)A1v;
            rowp[p] = (grow < split) ? (const void*)(A0 + (size_t)grow * K)
                                     : (const void*)(A1 + (size_t)(grow - split) * K);
        } else {
            rowp[p] = (const void*)((const _Float16*)A0v + (size_t)grow * K);
        }
    }

    auto loadA = [&](int c, half8* hv) {
#pragma unroll
        for (int p = 0; p < 2; ++p) {
            int idx = tid + p * 256;
            int kq = idx & 3;
            if (AF32) {
                const float* ap = (const float*)rowp[p];
                float4 v0 = *(const float4*)&ap[c * 32 + kq * 8];
                float4 v1 = *(const float4*)&ap[c * 32 + kq * 8 + 4];
                hv[p][0] = (_Float16)v0.x; hv[p][1] = (_Float16)v0.y;
                hv[p][2] = (_Float16)v0.z; hv[p][3] = (_Float16)v0.w;
                hv[p][4] = (_Float16)v1.x; hv[p][5] = (_Float16)v1.y;
                hv[p][6] = (_Float16)v1.z; hv[p][7] = (_Float16)v1.w;
            } else {
                const _Float16* ap = (const _Float16*)rowp[p];
                hv[p] = *(const half8*)&ap[c * 32 + kq * 8];
            }
        }
    };
    auto writeA = [&](half8* hv) {
#pragma unroll
        for (int p = 0; p < 2; ++p) {
            int idx = tid + p * 256;
            int row = idx >> 2, kq = idx & 3;
            *(half8*)&Asm[row * 40 + kq * 8] = hv[p];
        }
    };

    f32x4 acc[2][8];
#pragma unroll
    for (int rt = 0; rt < 2; ++rt)
#pragma unroll
        for (int ct = 0; ct < 8; ++ct) acc[rt][ct] = (f32x4){0.f, 0.f, 0.f, 0.f};

    constexpr int CH = K / 32;
    half8 cur[2], nxt[2];
    loadA(0, cur);
    writeA(cur);
    __syncthreads();
#pragma unroll
    for (int c = 0; c < CH; ++c) {
        if (c + 1 < CH) loadA(c + 1, nxt);  // global loads in flight during MFMAs
        half8 a0 = *(const half8*)&Asm[(w * 32 + l15) * 40 + g * 8];
        half8 a1 = *(const half8*)&Asm[(w * 32 + 16 + l15) * 40 + g * 8];
#pragma unroll
        for (int ct = 0; ct < 8; ++ct) {
            half8 b = *(const half8*)&Bsm[(ct * 16 + l15) * BSTR + c * 32 + g * 8];
            acc[0][ct] = __builtin_amdgcn_mfma_f32_16x16x32_f16(a0, b, acc[0][ct], 0, 0, 0);
            acc[1][ct] = __builtin_amdgcn_mfma_f32_16x16x32_f16(a1, b, acc[1][ct], 0, 0, 0);
        }
        __syncthreads();
        if (c + 1 < CH) {
            writeA(nxt);
            __syncthreads();
        }
    }

#pragma unroll
    for (int rt = 0; rt < 2; ++rt)
#pragma unroll
        for (int reg = 0; reg < 4; ++reg) {
            float s0 = 0.f, s1 = 0.f, d0 = 0.f, d1 = 0.f;
#pragma unroll
            for (int ct = 0; ct < 4; ++ct) {
                float v = acc[rt][ct][reg];
                s0 = fmaf(v, attL[ct * 16 + l15], s0);
                d0 = fmaf(v, attL[128 + ct * 16 + l15], d0);
            }
#pragma unroll
            for (int ct = 4; ct < 8; ++ct) {
                float v = acc[rt][ct][reg];
                s1 = fmaf(v, attL[ct * 16 + l15], s1);
                d1 = fmaf(v, attL[128 + ct * 16 + l15], d1);
            }
#pragma unroll
            for (int o = 1; o < 16; o <<= 1) {
                s0 += __shfl_xor(s0, o); s1 += __shfl_xor(s1, o);
                d0 += __shfl_xor(d0, o); d1 += __shfl_xor(d1, o);
            }
            if (l15 == 0) {
                int row = blkrow + w * 32 + rt * 16 + g * 4 + reg;
                *(float2*)&a_s[row * 2] = make_float2(s0, s1);
                *(float2*)&a_d[row * 2] = make_float2(d0, d1);
            }
        }

#pragma unroll
    for (int rt = 0; rt < 2; ++rt)
#pragma unroll
        for (int ct = 0; ct < 8; ++ct)
#pragma unroll
            for (int reg = 0; reg < 4; ++reg)
                epi[(w * 32 + rt * 16 + g * 4 + reg) * 136 + ct * 16 + l15] =
                    (_Float16)acc[rt][ct][reg];
    __syncthreads();
#pragma unroll
    for (int p = 0; p < 8; ++p) {
        int idx = tid + p * 256;
        int row = idx >> 4, c8 = idx & 15;
        *(half8*)&hh[(size_t)(blkrow + row) * 128 + c8 * 8] =
            *(const half8*)&epi[row * 136 + c8 * 8];
    }
}

// ---------------- GAT aggregation: one WAVE per dst node, both heads ----------------
// R8-benched structure (57-60us = gather floor): LDS-staged softmax, j-loop x4.
// Max pass deleted (logits O(0.3); verified absmax-neutral R10-R12).

template <bool CONCAT>
__global__ __launch_bounds__(256) void gat_agg_kernel(const __half* __restrict__ hh,
        const int* __restrict__ row_ptr, const int* __restrict__ src_sorted,
        const float* __restrict__ a_s, const float* __restrict__ a_d,
        const float* __restrict__ bias, void* __restrict__ outv) {
    __shared__ int   s_idx[4][64];
    __shared__ float s_w[4][64][2];
    int wid   = threadIdx.x >> 6;
    int lane  = threadIdx.x & 63;
    int dnode = blockIdx.x * 4 + wid;
    if (dnode >= N_NODES) return;
    int start = row_ptr[dnode], end = row_ptr[dnode + 1];
    int deg = end - start;
    float2 ad = *(const float2*)(a_d + dnode * 2);
    int hh_head = lane >> 5;
    float2 acc = {0.f, 0.f};
    float den0 = 0.f, den1 = 0.f;
    const __half2* h2 = (const __half2*)hh;

    if (deg <= 64) {  // fast path
        if (lane < deg) {
            int s = src_sorted[start + lane];
            float2 as = *(const float2*)(a_s + s * 2);
            float v0 = as.x + ad.x; v0 = v0 > 0.f ? v0 : NEG_SLOPE * v0;
            float v1 = as.y + ad.y; v1 = v1 > 0.f ? v1 : NEG_SLOPE * v1;
            float w0 = __expf(v0), w1 = __expf(v1);
            den0 = w0; den1 = w1;
            s_idx[wid][lane] = s;
            s_w[wid][lane][0] = w0;
            s_w[wid][lane][1] = w1;
        }
        for (int o = 32; o; o >>= 1) {
            den0 += __shfl_xor(den0, o);
            den1 += __shfl_xor(den1, o);
        }
        int j = 0;
#pragma unroll 1
        for (; j + 4 <= deg; j += 4) {
            int   si0 = s_idx[wid][j + 0], si1 = s_idx[wid][j + 1];
            int   si2 = s_idx[wid][j + 2], si3 = s_idx[wid][j + 3];
            float w0 = s_w[wid][j + 0][hh_head], w1 = s_w[wid][j + 1][hh_head];
            float w2 = s_w[wid][j + 2][hh_head], w3 = s_w[wid][j + 3][hh_head];
            float2 q0 = __half22float2(h2[(size_t)si0 * 64 + lane]);
            float2 q1 = __half22float2(h2[(size_t)si1 * 64 + lane]);
            float2 q2 = __half22float2(h2[(size_t)si2 * 64 + lane]);
            float2 q3 = __half22float2(h2[(size_t)si3 * 64 + lane]);
            acc.x = fmaf(w0, q0.x, acc.x); acc.y = fmaf(w0, q0.y, acc.y);
            acc.x = fmaf(w1, q1.x, acc.x); acc.y = fmaf(w1, q1.y, acc.y);
            acc.x = fmaf(w2, q2.x, acc.x); acc.y = fmaf(w2, q2.y, acc.y);
            acc.x = fmaf(w3, q3.x, acc.x); acc.y = fmaf(w3, q3.y, acc.y);
        }
        for (; j < deg; ++j) {
            int  si = s_idx[wid][j];
            float w = s_w[wid][j][hh_head];
            float2 v = __half22float2(h2[(size_t)si * 64 + lane]);
            acc.x = fmaf(w, v.x, acc.x);
            acc.y = fmaf(w, v.y, acc.y);
        }
    } else {  // general path (vanishingly rare for Poisson(16))
        for (int c0 = start; c0 < end; c0 += 64) {
            int len = min(64, end - c0);
            if (lane < len) {
                int s = src_sorted[c0 + lane];
                float2 as = *(const float2*)(a_s + s * 2);
                float v0 = as.x + ad.x; v0 = v0 > 0.f ? v0 : NEG_SLOPE * v0;
                float v1 = as.y + ad.y; v1 = v1 > 0.f ? v1 : NEG_SLOPE * v1;
                float w0 = __expf(v0), w1 = __expf(v1);
                den0 += w0; den1 += w1;
                s_idx[wid][lane] = s;
                s_w[wid][lane][0] = w0;
                s_w[wid][lane][1] = w1;
            }
            for (int j = 0; j < len; ++j) {
                int  si = s_idx[wid][j];
                float w = s_w[wid][j][hh_head];
                float2 v = __half22float2(h2[(size_t)si * 64 + lane]);
                acc.x = fmaf(w, v.x, acc.x);
                acc.y = fmaf(w, v.y, acc.y);
            }
        }
        for (int o = 32; o; o >>= 1) {
            den0 += __shfl_xor(den0, o);
            den1 += __shfl_xor(den1, o);
        }
    }

    float inv = 1.f / ((hh_head ? den1 : den0) + 1e-16f);
    float2 r = {acc.x * inv, acc.y * inv};

    if (CONCAT) {
        __half* out = (__half*)outv;
        float2 b = *(const float2*)(bias + lane * 2);
        __half2 o2 = __floats2half2_rn(r.x + b.x, r.y + b.y);
        *(__half2*)(out + (size_t)dnode * 128 + lane * 2) = o2;
    } else {
        float* out = (float*)outv;
        float ox = __shfl_xor(r.x, 32);
        float oy = __shfl_xor(r.y, 32);
        if (lane < 32) {
            float2 b = *(const float2*)(bias + lane * 2);
            float2 o2 = {0.5f * (r.x + ox) + b.x, 0.5f * (r.y + oy) + b.y};
            *(float2*)(out + (size_t)dnode * 64 + lane * 2) = o2;
        }
    }
}

// ---------------- final pair dot ----------------

__global__ void pair_dot_kernel(const float* __restrict__ emb, const int* __restrict__ ui,
                                const int* __restrict__ ii, float* __restrict__ out, int B) {
    int w    = blockIdx.x * 4 + (threadIdx.x >> 6);
    int lane = threadIdx.x & 63;
    if (w >= B) return;
    float a = emb[(size_t)ui[w] * 64 + lane];
    float b = emb[(size_t)(NU_NODES + ii[w]) * 64 + lane];
    float p = a * b;
    for (int o = 32; o; o >>= 1) p += __shfl_xor(p, o);
    if (lane == 0) out[w] = p;
}

extern "C" void kernel_launch(void* const* d_in, const int* in_sizes, int n_in,
                              void* d_out, int out_size, void* d_ws, size_t ws_size,
                              hipStream_t stream) {
    const float* Gu       = (const float*)d_in[0];
    const float* Gi       = (const float*)d_in[1];
    const float* W0       = (const float*)d_in[2];
    const float* att_src0 = (const float*)d_in[3];
    const float* att_dst0 = (const float*)d_in[4];
    const float* b0       = (const float*)d_in[5];
    const float* W1       = (const float*)d_in[6];
    const float* att_src1 = (const float*)d_in[7];
    const float* att_dst1 = (const float*)d_in[8];
    const float* b1       = (const float*)d_in[9];
    const int* edge_index = (const int*)d_in[10];
    const int* user_idx   = (const int*)d_in[11];
    const int* item_idx   = (const int*)d_in[12];
    float* outp           = (float*)d_out;

    const int N = N_NODES, E = E_EDGES;
    char* wsp = (char*)d_ws;
    auto alloc = [&](size_t bytes) {
        void* p = wsp;
        wsp += (bytes + 255) & ~(size_t)255;
        return p;
    };
    float*  emb = (float*)alloc((size_t)N * 64 * 4);    // final embeddings (f32)
    __half* hh  = (__half*)alloc((size_t)N * 128 * 2);  // fp16 h (both layers)
    __half* x1h = (__half*)alloc((size_t)N * 128 * 2);  // layer0 output (fp16)
    float*  a_s = (float*)alloc((size_t)N * 2 * 4);
    float*  a_d = (float*)alloc((size_t)N * 2 * 4);
    int* row_ptr     = (int*)alloc((size_t)(N + 1) * 4);
    int* src_sorted  = (int*)alloc((size_t)E * 4);
    int* bucketCount = (int*)alloc((NBUCK + 1) * 4);
    int* bucket_ptr  = (int*)alloc((NBUCK + 1) * 4);
    int* gfill       = (int*)alloc((NBUCK + 1) * 4);
    // pk only lives during CSR build; x1h only written after -> overlay
    unsigned long long* pk = (unsigned long long*)x1h;

    const int* esrc = edge_index;
    const int* edst = edge_index + E;

    hipMemsetAsync(bucketCount, 0, (NBUCK + 1) * 4, stream);

    // layer-0 GEMM with FUSED bucket histogram (csr hist overlaps GEMM compute)
    gemm_mfma<64, true, true><<<N / 128, 256, 0, stream>>>(
        Gu, Gi, NU_NODES, W0, att_src0, att_dst0, hh, a_s, a_d, edst, bucketCount);

    // CSR chain (needs bucketCount; independent of a_s/a_d/hh)
    topscan_kernel<<<1, 512, 0, stream>>>(bucketCount, bucket_ptr, gfill);
    int nblk = (E + SCHUNK - 1) / SCHUNK;
    bscatter_kernel<<<nblk, 512, 0, stream>>>(esrc, edst, gfill, pk, E);
    escatter2_kernel<<<NBUCK, 256, 0, stream>>>(pk, bucket_ptr, row_ptr, src_sorted);

    // layer 0 aggregation
    gat_agg_kernel<true><<<(N + 3) / 4, 256, 0, stream>>>(hh, row_ptr, src_sorted, a_s, a_d,
                                                          b0, x1h);

    // layer 1
    gemm_mfma<128, false, false><<<N / 128, 256, 0, stream>>>(
        x1h, x1h, N, W1, att_src1, att_dst1, hh, a_s, a_d, nullptr, nullptr);
    gat_agg_kernel<false><<<(N + 3) / 4, 256, 0, stream>>>(hh, row_ptr, src_sorted, a_s, a_d,
                                                           b1, emb);

    // final dot
    pair_dot_kernel<<<B_PAIRS / 4, 256, 0, stream>>>(emb, user_idx, item_idx, outp, B_PAIRS);
}

// Round 14
// 222.298 us; speedup vs baseline: 1.4083x; 1.0002x over previous
//
#include <hip/hip_runtime.h>
#include <hip/hip_fp16.h>
#include <math.h>

#define N_NODES   80000
#define NU_NODES  40000
#define E_EDGES   1280000
#define B_PAIRS   8192
#define NEG_SLOPE 0.2f
#define NBUCK     313   // ceil(N_NODES / 256)
#define SCHUNK    2048  // edges per binning block
#define NSLICE    5     // src slices of 16384 nodes (4MB of fp16 h each)

typedef _Float16 half8 __attribute__((ext_vector_type(8)));
typedef float    f32x4 __attribute__((ext_vector_type(4)));

// ---------------- CSR build ----------------
// bucket histogram fused into gemm_mfma<64> (HIST=true). Then:
// topscan -> bscatter -> escatter2 (derives row_ptr; lists (dst,src-slice)-sorted).

__global__ __launch_bounds__(512) void topscan_kernel(const int* __restrict__ bucketCount,
                                                      int* __restrict__ bucket_ptr,
                                                      int* __restrict__ gfill) {
    __shared__ int tmp[512];
    int t = threadIdx.x;
    int v = (t < NBUCK) ? bucketCount[t] : 0;
    tmp[t] = v;
    __syncthreads();
    for (int off = 1; off < 512; off <<= 1) {
        int x = (t >= off) ? tmp[t - off] : 0;
        __syncthreads();
        tmp[t] += x;
        __syncthreads();
    }
    int excl = tmp[t] - v;
    if (t < NBUCK) {
        bucket_ptr[t] = excl;
        gfill[t]      = excl;
        if (t == NBUCK - 1) bucket_ptr[NBUCK] = excl + v;
    }
}

__global__ __launch_bounds__(512) void bscatter_kernel(const int* __restrict__ src,
                                                       const int* __restrict__ dst,
                                                       int* __restrict__ gfill,
                                                       unsigned long long* __restrict__ pk,
                                                       int E) {
    __shared__ int histL[NBUCK];
    __shared__ int baseL[NBUCK];
    __shared__ int rankL[NBUCK];
    for (int i = threadIdx.x; i < NBUCK; i += 512) { histL[i] = 0; rankL[i] = 0; }
    __syncthreads();
    int base = blockIdx.x * SCHUNK;
#pragma unroll
    for (int r = 0; r < SCHUNK / 512; ++r) {
        int e = base + r * 512 + threadIdx.x;
        if (e < E) atomicAdd(&histL[dst[e] >> 8], 1);
    }
    __syncthreads();
    for (int i = threadIdx.x; i < NBUCK; i += 512)
        baseL[i] = histL[i] ? atomicAdd(&gfill[i], histL[i]) : 0;
    __syncthreads();
#pragma unroll
    for (int r = 0; r < SCHUNK / 512; ++r) {
        int e = base + r * 512 + threadIdx.x;
        if (e < E) {
            int d = dst[e];
            int b = d >> 8;
            int rk = atomicAdd(&rankL[b], 1);
            pk[baseL[b] + rk] = ((unsigned long long)(unsigned)d << 32) | (unsigned)src[e];
        }
    }
}

// Per bucket: 2-level count (node-low8, src-slice) -> in-block scan (1280 bins)
// -> row_ptr write -> scatter. Lists come out (dst, src-slice)-sorted so the
// aggregation's gathers sweep the src table in ~4MB windows (L2 co-traversal).
__global__ __launch_bounds__(256) void escatter2_kernel(
        const unsigned long long* __restrict__ pk, const int* __restrict__ bucket_ptr,
        int* __restrict__ row_ptr, int* __restrict__ src_sorted) {
    __shared__ int cnt[256 * NSLICE];   // counts then fill-cursors
    __shared__ int seg[256 * NSLICE];   // segment base offsets
    __shared__ int tsum[256];
    __shared__ int tmp[256];
    int b = blockIdx.x;
    int t = threadIdx.x;
    int node0 = b << 8;
    int s = bucket_ptr[b], e = bucket_ptr[b + 1];
    for (int i = t; i < 256 * NSLICE; i += 256) cnt[i] = 0;
    __syncthreads();
    for (int k = s + t; k < e; k += 256) {
        unsigned long long p = pk[k];
        int lo  = (int)(p >> 32) & 255;
        int src = (int)(unsigned)p;
        atomicAdd(&cnt[lo * NSLICE + (src >> 14)], 1);
    }
    __syncthreads();
    // thread t owns node lo=t's NSLICE bins: local prefix, then block scan of totals
    int loc[NSLICE];
    int run = 0;
#pragma unroll
    for (int q = 0; q < NSLICE; ++q) { loc[q] = run; run += cnt[t * NSLICE + q]; }
    tsum[t] = run;
    tmp[t]  = run;
    __syncthreads();
    for (int off = 1; off < 256; off <<= 1) {
        int x = (t >= off) ? tmp[t - off] : 0;
        __syncthreads();
        tmp[t] += x;
        __syncthreads();
    }
    int excl = tmp[t] - run;  // exclusive node offset within bucket
#pragma unroll
    for (int q = 0; q < NSLICE; ++q) seg[t * NSLICE + q] = s + excl + loc[q];
    int node = node0 + t;
    if (node < N_NODES) row_ptr[node] = s + excl;
    if (b == NBUCK - 1 && t == 0) row_ptr[N_NODES] = e;
    for (int i = t; i < 256 * NSLICE; i += 256) cnt[i] = 0;
    __syncthreads();
    for (int k = s + t; k < e; k += 256) {
        unsigned long long p = pk[k];
        int lo  = (int)(p >> 32) & 255;
        int src = (int)(unsigned)p;
        int bin = lo * NSLICE + (src >> 14);
        int pos = atomicAdd(&cnt[bin], 1);
        src_sorted[seg[bin] + pos] = src;
    }
}

// ---------------- MFMA f16 GEMM + fused att-dot epilogue (+optional edge hist) ----

template <int K, bool AF32, bool HIST>
__global__ __launch_bounds__(256) void gemm_mfma(const void* __restrict__ A0v,
                                                 const void* __restrict__ A1v, int split,
                                                 const float* __restrict__ W,
                                                 const float* __restrict__ attS,
                                                 const float* __restrict__ attD,
                                                 __half* __restrict__ hh,
                                                 float* __restrict__ a_s,
                                                 float* __restrict__ a_d,
                                                 const int* __restrict__ edst,
                                                 int* __restrict__ bucketCount) {
    constexpr int BSTR   = K + 8;
    constexpr int BSM_SZ = 128 * BSTR * 2;
    constexpr int EPI_SZ = 128 * 136 * 2;
    constexpr int ATT_OFF = (10240 + BSM_SZ > EPI_SZ) ? (10240 + BSM_SZ) : EPI_SZ;
    __shared__ __align__(16) char lds[ATT_OFF + 1024 + (HIST ? (NBUCK + 7) * 4 : 4)];
    _Float16* Asm  = (_Float16*)lds;
    _Float16* Bsm  = (_Float16*)(lds + 10240);
    _Float16* epi  = (_Float16*)lds;
    float*    attL = (float*)(lds + ATT_OFF);
    int*      histL = (int*)(lds + ATT_OFF + 1024);

    const int tid    = threadIdx.x;
    const int w      = tid >> 6;
    const int l      = tid & 63;
    const int l15    = l & 15;
    const int g      = l >> 4;
    const int blkrow = blockIdx.x * 128;

    if (HIST) {
        for (int i = tid; i < NBUCK; i += 256) histL[i] = 0;
        __syncthreads();
        int base = blockIdx.x * SCHUNK;
#pragma unroll
        for (int r = 0; r < SCHUNK / 256; ++r)
            atomicAdd(&histL[edst[base + r * 256 + tid] >> 8], 1);
        __syncthreads();
        for (int i = tid; i < NBUCK; i += 256)
            if (histL[i]) atomicAdd(&bucketCount[i], histL[i]);
    }

    attL[tid] = (tid < 128) ? attS[tid] : attD[tid - 128];

    for (int idx = tid; idx < K * 32; idx += 256) {
        int k = idx >> 5, c4 = idx & 31;
        float4 wv = *(const float4*)&W[(size_t)k * 128 + c4 * 4];
        Bsm[(c4 * 4 + 0) * BSTR + k] = (_Float16)wv.x;
        Bsm[(c4 * 4 + 1) * BSTR + k] = (_Float16)wv.y;
        Bsm[(c4 * 4 + 2) * BSTR + k] = (_Float16)wv.z;
        Bsm[(c4 * 4 + 3) * BSTR + k] = (_Float16)wv.w;
    }

    const void* rowp[2];
#pragma unroll
    for (int p = 0; p < 2; ++p) {
        int idx = tid + p * 256;
        int row = idx >> 2;
        int grow = blkrow + row;
        if (AF32) {
            const float* A0 = (const float*)A0v;
            const float* A1 = (const float*)A1v;
            rowp[p] = (grow < split) ? (const void*)(A0 + (size_t)grow * K)
                                     : (const void*)(A1 + (size_t)(grow - split) * K);
        } else {
            rowp[p] = (const void*)((const _Float16*)A0v + (size_t)grow * K);
        }
    }

    auto loadA = [&](int c, half8* hv) {
#pragma unroll
        for (int p = 0; p < 2; ++p) {
            int idx = tid + p * 256;
            int kq = idx & 3;
            if (AF32) {
                const float* ap = (const float*)rowp[p];
                float4 v0 = *(const float4*)&ap[c * 32 + kq * 8];
                float4 v1 = *(const float4*)&ap[c * 32 + kq * 8 + 4];
                hv[p][0] = (_Float16)v0.x; hv[p][1] = (_Float16)v0.y;
                hv[p][2] = (_Float16)v0.z; hv[p][3] = (_Float16)v0.w;
                hv[p][4] = (_Float16)v1.x; hv[p][5] = (_Float16)v1.y;
                hv[p][6] = (_Float16)v1.z; hv[p][7] = (_Float16)v1.w;
            } else {
                const _Float16* ap = (const _Float16*)rowp[p];
                hv[p] = *(const half8*)&ap[c * 32 + kq * 8];
            }
        }
    };
    auto writeA = [&](half8* hv) {
#pragma unroll
        for (int p = 0; p < 2; ++p) {
            int idx = tid + p * 256;
            int row = idx >> 2, kq = idx & 3;
            *(half8*)&Asm[row * 40 + kq * 8] = hv[p];
        }
    };

    f32x4 acc[2][8];
#pragma unroll
    for (int rt = 0; rt < 2; ++rt)
#pragma unroll
        for (int ct = 0; ct < 8; ++ct) acc[rt][ct] = (f32x4){0.f, 0.f, 0.f, 0.f};

    constexpr int CH = K / 32;
    half8 cur[2], nxt[2];
    loadA(0, cur);
    writeA(cur);
    __syncthreads();
#pragma unroll
    for (int c = 0; c < CH; ++c) {
        if (c + 1 < CH) loadA(c + 1, nxt);
        half8 a0 = *(const half8*)&Asm[(w * 32 + l15) * 40 + g * 8];
        half8 a1 = *(const half8*)&Asm[(w * 32 + 16 + l15) * 40 + g * 8];
#pragma unroll
        for (int ct = 0; ct < 8; ++ct) {
            half8 b = *(const half8*)&Bsm[(ct * 16 + l15) * BSTR + c * 32 + g * 8];
            acc[0][ct] = __builtin_amdgcn_mfma_f32_16x16x32_f16(a0, b, acc[0][ct], 0, 0, 0);
            acc[1][ct] = __builtin_amdgcn_mfma_f32_16x16x32_f16(a1, b, acc[1][ct], 0, 0, 0);
        }
        __syncthreads();
        if (c + 1 < CH) {
            writeA(nxt);
            __syncthreads();
        }
    }

#pragma unroll
    for (int rt = 0; rt < 2; ++rt)
#pragma unroll
        for (int reg = 0; reg < 4; ++reg) {
            float s0 = 0.f, s1 = 0.f, d0 = 0.f, d1 = 0.f;
#pragma unroll
            for (int ct = 0; ct < 4; ++ct) {
                float v = acc[rt][ct][reg];
                s0 = fmaf(v, attL[ct * 16 + l15], s0);
                d0 = fmaf(v, attL[128 + ct * 16 + l15], d0);
            }
#pragma unroll
            for (int ct = 4; ct < 8; ++ct) {
                float v = acc[rt][ct][reg];
                s1 = fmaf(v, attL[ct * 16 + l15], s1);
                d1 = fmaf(v, attL[128 + ct * 16 + l15], d1);
            }
#pragma unroll
            for (int o = 1; o < 16; o <<= 1) {
                s0 += __shfl_xor(s0, o); s1 += __shfl_xor(s1, o);
                d0 += __shfl_xor(d0, o); d1 += __shfl_xor(d1, o);
            }
            if (l15 == 0) {
                int row = blkrow + w * 32 + rt * 16 + g * 4 + reg;
                *(float2*)&a_s[row * 2] = make_float2(s0, s1);
                *(float2*)&a_d[row * 2] = make_float2(d0, d1);
            }
        }

#pragma unroll
    for (int rt = 0; rt < 2; ++rt)
#pragma unroll
        for (int ct = 0; ct < 8; ++ct)
#pragma unroll
            for (int reg = 0; reg < 4; ++reg)
                epi[(w * 32 + rt * 16 + g * 4 + reg) * 136 + ct * 16 + l15] =
                    (_Float16)acc[rt][ct][reg];
    __syncthreads();
#pragma unroll
    for (int p = 0; p < 8; ++p) {
        int idx = tid + p * 256;
        int row = idx >> 4, c8 = idx & 15;
        *(half8*)&hh[(size_t)(blkrow + row) * 128 + c8 * 8] =
            *(const half8*)&epi[row * 136 + c8 * 8];
    }
}

// ---------------- GAT aggregation: one WAVE per dst node, both heads ----------------
// R8-benched structure; lists are (dst,src-slice)-sorted by escatter2 so the
// PV gathers co-traverse the h table in ~4MB windows.

template <bool CONCAT>
__global__ __launch_bounds__(256) void gat_agg_kernel(const __half* __restrict__ hh,
        const int* __restrict__ row_ptr, const int* __restrict__ src_sorted,
        const float* __restrict__ a_s, const float* __restrict__ a_d,
        const float* __restrict__ bias, void* __restrict__ outv) {
    __shared__ int   s_idx[4][64];
    __shared__ float s_w[4][64][2];
    int wid   = threadIdx.x >> 6;
    int lane  = threadIdx.x & 63;
    int dnode = blockIdx.x * 4 + wid;
    if (dnode >= N_NODES) return;
    int start = row_ptr[dnode], end = row_ptr[dnode + 1];
    int deg = end - start;
    float2 ad = *(const float2*)(a_d + dnode * 2);
    int hh_head = lane >> 5;
    float2 acc = {0.f, 0.f};
    float den0 = 0.f, den1 = 0.f;
    const __half2* h2 = (const __half2*)hh;

    if (deg <= 64) {  // fast path
        if (lane < deg) {
            int s = src_sorted[start + lane];
            float2 as = *(const float2*)(a_s + s * 2);
            float v0 = as.x + ad.x; v0 = v0 > 0.f ? v0 : NEG_SLOPE * v0;
            float v1 = as.y + ad.y; v1 = v1 > 0.f ? v1 : NEG_SLOPE * v1;
            float w0 = __expf(v0), w1 = __expf(v1);
            den0 = w0; den1 = w1;
            s_idx[wid][lane] = s;
            s_w[wid][lane][0] = w0;
            s_w[wid][lane][1] = w1;
        }
        for (int o = 32; o; o >>= 1) {
            den0 += __shfl_xor(den0, o);
            den1 += __shfl_xor(den1, o);
        }
        int j = 0;
#pragma unroll 1
        for (; j + 4 <= deg; j += 4) {
            int   si0 = s_idx[wid][j + 0], si1 = s_idx[wid][j + 1];
            int   si2 = s_idx[wid][j + 2], si3 = s_idx[wid][j + 3];
            float w0 = s_w[wid][j + 0][hh_head], w1 = s_w[wid][j + 1][hh_head];
            float w2 = s_w[wid][j + 2][hh_head], w3 = s_w[wid][j + 3][hh_head];
            float2 q0 = __half22float2(h2[(size_t)si0 * 64 + lane]);
            float2 q1 = __half22float2(h2[(size_t)si1 * 64 + lane]);
            float2 q2 = __half22float2(h2[(size_t)si2 * 64 + lane]);
            float2 q3 = __half22float2(h2[(size_t)si3 * 64 + lane]);
            acc.x = fmaf(w0, q0.x, acc.x); acc.y = fmaf(w0, q0.y, acc.y);
            acc.x = fmaf(w1, q1.x, acc.x); acc.y = fmaf(w1, q1.y, acc.y);
            acc.x = fmaf(w2, q2.x, acc.x); acc.y = fmaf(w2, q2.y, acc.y);
            acc.x = fmaf(w3, q3.x, acc.x); acc.y = fmaf(w3, q3.y, acc.y);
        }
        for (; j < deg; ++j) {
            int  si = s_idx[wid][j];
            float w = s_w[wid][j][hh_head];
            float2 v = __half22float2(h2[(size_t)si * 64 + lane]);
            acc.x = fmaf(w, v.x, acc.x);
            acc.y = fmaf(w, v.y, acc.y);
        }
    } else {  // general path (vanishingly rare for Poisson(16))
        for (int c0 = start; c0 < end; c0 += 64) {
            int len = min(64, end - c0);
            if (lane < len) {
                int s = src_sorted[c0 + lane];
                float2 as = *(const float2*)(a_s + s * 2);
                float v0 = as.x + ad.x; v0 = v0 > 0.f ? v0 : NEG_SLOPE * v0;
                float v1 = as.y + ad.y; v1 = v1 > 0.f ? v1 : NEG_SLOPE * v1;
                float w0 = __expf(v0), w1 = __expf(v1);
                den0 += w0; den1 += w1;
                s_idx[wid][lane] = s;
                s_w[wid][lane][0] = w0;
                s_w[wid][lane][1] = w1;
            }
            for (int j = 0; j < len; ++j) {
                int  si = s_idx[wid][j];
                float w = s_w[wid][j][hh_head];
                float2 v = __half22float2(h2[(size_t)si * 64 + lane]);
                acc.x = fmaf(w, v.x, acc.x);
                acc.y = fmaf(w, v.y, acc.y);
            }
        }
        for (int o = 32; o; o >>= 1) {
            den0 += __shfl_xor(den0, o);
            den1 += __shfl_xor(den1, o);
        }
    }

    float inv = 1.f / ((hh_head ? den1 : den0) + 1e-16f);
    float2 r = {acc.x * inv, acc.y * inv};

    if (CONCAT) {
        __half* out = (__half*)outv;
        float2 b = *(const float2*)(bias + lane * 2);
        __half2 o2 = __floats2half2_rn(r.x + b.x, r.y + b.y);
        *(__half2*)(out + (size_t)dnode * 128 + lane * 2) = o2;
    } else {
        float* out = (float*)outv;
        float ox = __shfl_xor(r.x, 32);
        float oy = __shfl_xor(r.y, 32);
        if (lane < 32) {
            float2 b = *(const float2*)(bias + lane * 2);
            float2 o2 = {0.5f * (r.x + ox) + b.x, 0.5f * (r.y + oy) + b.y};
            *(float2*)(out + (size_t)dnode * 64 + lane * 2) = o2;
        }
    }
}

// ---------------- final pair dot ----------------

__global__ void pair_dot_kernel(const float* __restrict__ emb, const int* __restrict__ ui,
                                const int* __restrict__ ii, float* __restrict__ out, int B) {
    int w    = blockIdx.x * 4 + (threadIdx.x >> 6);
    int lane = threadIdx.x & 63;
    if (w >= B) return;
    float a = emb[(size_t)ui[w] * 64 + lane];
    float b = emb[(size_t)(NU_NODES + ii[w]) * 64 + lane];
    float p = a * b;
    for (int o = 32; o; o >>= 1) p += __shfl_xor(p, o);
    if (lane == 0) out[w] = p;
}

extern "C" void kernel_launch(void* const* d_in, const int* in_sizes, int n_in,
                              void* d_out, int out_size, void* d_ws, size_t ws_size,
                              hipStream_t stream) {
    const float* Gu       = (const float*)d_in[0];
    const float* Gi       = (const float*)d_in[1];
    const float* W0       = (const float*)d_in[2];
    const float* att_src0 = (const float*)d_in[3];
    const float* att_dst0 = (const float*)d_in[4];
    const float* b0       = (const float*)d_in[5];
    const float* W1       = (const float*)d_in[6];
    const float* att_src1 = (const float*)d_in[7];
    const float* att_dst1 = (const float*)d_in[8];
    const float* b1       = (const float*)d_in[9];
    const int* edge_index = (const int*)d_in[10];
    const int* user_idx   = (const int*)d_in[11];
    const int* item_idx   = (const int*)d_in[12];
    float* outp           = (float*)d_out;

    const int N = N_NODES, E = E_EDGES;
    char* wsp = (char*)d_ws;
    auto alloc = [&](size_t bytes) {
        void* p = wsp;
        wsp += (bytes + 255) & ~(size_t)255;
        return p;
    };
    float*  emb = (float*)alloc((size_t)N * 64 * 4);    // final embeddings (f32)
    __half* hh  = (__half*)alloc((size_t)N * 128 * 2);  // fp16 h (both layers)
    __half* x1h = (__half*)alloc((size_t)N * 128 * 2);  // layer0 output (fp16)
    float*  a_s = (float*)alloc((size_t)N * 2 * 4);
    float*  a_d = (float*)alloc((size_t)N * 2 * 4);
    int* row_ptr     = (int*)alloc((size_t)(N + 1) * 4);
    int* src_sorted  = (int*)alloc((size_t)E * 4);
    int* bucketCount = (int*)alloc((NBUCK + 1) * 4);
    int* bucket_ptr  = (int*)alloc((NBUCK + 1) * 4);
    int* gfill       = (int*)alloc((NBUCK + 1) * 4);
    // pk only lives during CSR build; x1h only written after -> overlay
    unsigned long long* pk = (unsigned long long*)x1h;

    const int* esrc = edge_index;
    const int* edst = edge_index + E;

    hipMemsetAsync(bucketCount, 0, (NBUCK + 1) * 4, stream);

    // layer-0 GEMM with FUSED bucket histogram (csr hist overlaps GEMM compute)
    gemm_mfma<64, true, true><<<N / 128, 256, 0, stream>>>(
        Gu, Gi, NU_NODES, W0, att_src0, att_dst0, hh, a_s, a_d, edst, bucketCount);

    // CSR chain
    topscan_kernel<<<1, 512, 0, stream>>>(bucketCount, bucket_ptr, gfill);
    int nblk = (E + SCHUNK - 1) / SCHUNK;
    bscatter_kernel<<<nblk, 512, 0, stream>>>(esrc, edst, gfill, pk, E);
    escatter2_kernel<<<NBUCK, 256, 0, stream>>>(pk, bucket_ptr, row_ptr, src_sorted);

    // layer 0 aggregation
    gat_agg_kernel<true><<<(N + 3) / 4, 256, 0, stream>>>(hh, row_ptr, src_sorted, a_s, a_d,
                                                          b0, x1h);

    // layer 1
    gemm_mfma<128, false, false><<<N / 128, 256, 0, stream>>>(
        x1h, x1h, N, W1, att_src1, att_dst1, hh, a_s, a_d, nullptr, nullptr);
    gat_agg_kernel<false><<<(N + 3) / 4, 256, 0, stream>>>(hh, row_ptr, src_sorted, a_s, a_d,
                                                           b1, emb);

    // final dot
    pair_dot_kernel<<<B_PAIRS / 4, 256, 0, stream>>>(emb, user_idx, item_idx, outp, B_PAIRS);
}